// Round 6
// baseline (189.700 us; speedup 1.0000x reference)
//
#include <hip/hip_runtime.h>
#include <stdint.h>

// VQ-VAE quantization: B=131072 rows of z (D=64) vs N_E=1024 codes.
// Outputs (flat f32): z_q [131072*64] | loss [1] | idx [131072] | var(idx,ddof=1) [1]
//
// R6: code-stationary with ASM-PINNED registers (R5's remat defeated) +
// 32-row double-subtile iterations + cross-iteration z prefetch.
//  K0 vq_prep: codebook -> -2e bf16 MFMA A-frags + ||e||^2+0.5.
//  K1 vq_dist: 1024 blocks x 512 thr (8 waves). Wave w holds code tiles
//     w*8..w*8+7 (128 codes) in 64 VGPRs, kept live by asm keep-alives.
//     4 iterations x 32 z-rows; next iteration's z prefetched into regs.
//  K2 vq_out: combine 8 per-wave keys/row -> idx; gather z_q; partials.
//  K3 vq_final: scalar reduce.
// key = (float_bits(0.5+||e||^2-2z.e) & ~1023) | code ; unsigned min == argmin.

typedef __attribute__((ext_vector_type(8))) __bf16 bf16x8;
typedef __attribute__((ext_vector_type(4))) float f32x4;

#define OUT_LOSS 8388608
#define OUT_IDX  8388609
#define OUT_VAR  8519681

// workspace layout (bytes); total ~4.9 MB
#define WS_LOSS  0                  // float[2048] per-block loss partials
#define WS_S1    8192               // int[2048] sum(idx)
#define WS_S2    16384              // int[2048] sum(idx^2)
#define WS_EFRAG 24576              // bf16x8[64 tiles * 2 ksteps * 64 lanes] = 128 KB
#define WS_EE    155648             // float[1024] ||e||^2 + 0.5 (4 KB)
#define WS_KEY   159744             // unsigned[131072][8] per-wave keys (4 MB)
#define WS_ZZ    4354048            // float[131072] ||z_row||^2 (512 KB)

// ---- K0: prep codebook fragments -----------------------------------------
// A-frag for mfma_f32_16x16x32_bf16: lane l holds code row (t*16 + (l&15)),
// k = kstep*32 + (l>>4)*8 + i. Values are -2*e.
__global__ void vq_prep(const float* __restrict__ emb, char* __restrict__ ws) {
  bf16x8* efrag = (bf16x8*)(ws + WS_EFRAG);
  float* eeoff = (float*)(ws + WS_EE);
  const int t = blockIdx.x;    // tile 0..63
  const int l = threadIdx.x;   // 0..63
  const int n = t * 16 + (l & 15);
  const int kb0 = (l >> 4) * 8;
  const float* er = emb + n * 64;
  for (int j = 0; j < 2; ++j) {
    const int kb = j * 32 + kb0;
    bf16x8 h;
#pragma unroll
    for (int i = 0; i < 8; ++i) h[i] = (__bf16)(-2.0f * er[kb + i]);
    efrag[(t * 2 + j) * 64 + l] = h;
  }
  if (l < 16) {
    const float* e2 = emb + (t * 16 + l) * 64;
    float s = 0.f;
#pragma unroll
    for (int d = 0; d < 64; ++d) s += e2[d] * e2[d];
    eeoff[t * 16 + l] = s + 0.5f;
  }
}

// ---- K1: distances + per-wave argmin (no barriers, no LDS) -----------------
// 1024 blocks x 512 thr; block covers 128 rows; wave covers codes w*128..+127.
__global__ void __launch_bounds__(512, 4) vq_dist(
    const float* __restrict__ z, char* __restrict__ ws) {
  const int tid = threadIdx.x;
  const int wave = tid >> 6, lane = tid & 63;
  const int lr = lane & 15, ksl = lane >> 4;
  const int k0 = ksl * 8;

  const bf16x8* efrag = (const bf16x8*)(ws + WS_EFRAG);
  const f32x4* eeoff4 = (const f32x4*)(ws + WS_EE);
  unsigned* wkey = (unsigned*)(ws + WS_KEY);
  float* wzz = (float*)(ws + WS_ZZ);

  // stationary codes: 8 tiles x (e0,e1) = 64 VGPR, asm-pinned in the loop
  bf16x8 e0b[8], e1b[8];
#pragma unroll
  for (int tt = 0; tt < 8; ++tt) {
    const int t = wave * 8 + tt;
    e0b[tt] = efrag[(t * 2 + 0) * 64 + lane];
    e1b[tt] = efrag[(t * 2 + 1) * 64 + lane];
  }
  const unsigned k4 = (unsigned)(ksl * 4);

  const int row0 = blockIdx.x * 128;
  // z for iteration 0: subtile A = rows row0+lr, B = rows row0+16+lr;
  // this lane holds its ksl's 16 dims of each (4 f32x4 per subtile).
  f32x4 c[8];
  {
    const float* zra = z + (size_t)(row0 + lr) * 64;
    const float* zrb = z + (size_t)(row0 + 16 + lr) * 64;
    c[0] = *(const f32x4*)(zra + k0);      c[1] = *(const f32x4*)(zra + k0 + 4);
    c[2] = *(const f32x4*)(zra + 32 + k0); c[3] = *(const f32x4*)(zra + 32 + k0 + 4);
    c[4] = *(const f32x4*)(zrb + k0);      c[5] = *(const f32x4*)(zrb + k0 + 4);
    c[6] = *(const f32x4*)(zrb + 32 + k0); c[7] = *(const f32x4*)(zrb + 32 + k0 + 4);
  }

#pragma unroll
  for (int it = 0; it < 4; ++it) {
    const int rbase = row0 + it * 32;
    // 1) convert current z to bf16 B-fragments
    bf16x8 zfa0, zfa1, zfb0, zfb1;
#pragma unroll
    for (int i = 0; i < 4; ++i) {
      zfa0[i] = (__bf16)c[0][i]; zfa0[4 + i] = (__bf16)c[1][i];
      zfa1[i] = (__bf16)c[2][i]; zfa1[4 + i] = (__bf16)c[3][i];
      zfb0[i] = (__bf16)c[4][i]; zfb0[4 + i] = (__bf16)c[5][i];
      zfb1[i] = (__bf16)c[6][i]; zfb1[4 + i] = (__bf16)c[7][i];
    }
    // 2) ||z||^2 partials (wave 0 only; consumes c before overwrite)
    if (wave == 0) {
      float sa = 0.f, sb = 0.f;
#pragma unroll
      for (int i = 0; i < 4; ++i) {
        sa += c[0][i] * c[0][i] + c[1][i] * c[1][i] + c[2][i] * c[2][i] + c[3][i] * c[3][i];
        sb += c[4][i] * c[4][i] + c[5][i] * c[5][i] + c[6][i] * c[6][i] + c[7][i] * c[7][i];
      }
      sa += __shfl_xor(sa, 16, 64); sa += __shfl_xor(sa, 32, 64);
      sb += __shfl_xor(sb, 16, 64); sb += __shfl_xor(sb, 32, 64);
      if (ksl == 0) { wzz[rbase + lr] = sa; wzz[rbase + 16 + lr] = sb; }
    }
    // 3) prefetch next iteration's z (32 VGPR in flight across the MFMA body)
    if (it < 3) {
      const float* zra = z + (size_t)(rbase + 32 + lr) * 64;
      const float* zrb = z + (size_t)(rbase + 48 + lr) * 64;
      c[0] = *(const f32x4*)(zra + k0);      c[1] = *(const f32x4*)(zra + k0 + 4);
      c[2] = *(const f32x4*)(zra + 32 + k0); c[3] = *(const f32x4*)(zra + 32 + k0 + 4);
      c[4] = *(const f32x4*)(zrb + k0);      c[5] = *(const f32x4*)(zrb + k0 + 4);
      c[6] = *(const f32x4*)(zrb + 32 + k0); c[7] = *(const f32x4*)(zrb + 32 + k0 + 4);
    }
    // 4) pin the stationary codes: each iteration "modifies" them, so the
    //    allocator cannot rematerialize the loads (R5's failure mode)
#pragma unroll
    for (int tt = 0; tt < 8; ++tt) {
      f32x4 p0 = __builtin_bit_cast(f32x4, e0b[tt]);
      f32x4 p1 = __builtin_bit_cast(f32x4, e1b[tt]);
      asm volatile("" : "+v"(p0), "+v"(p1));
      e0b[tt] = __builtin_bit_cast(bf16x8, p0);
      e1b[tt] = __builtin_bit_cast(bf16x8, p1);
    }
    // 5) MFMAs + packed-key argmin
    unsigned rka = 0xFFFFFFFFu, rkb = 0xFFFFFFFFu;
#pragma unroll
    for (int tt = 0; tt < 8; ++tt) {
      const int t = wave * 8 + tt;
      const f32x4 ee = eeoff4[t * 4 + ksl];
      f32x4 a = __builtin_amdgcn_mfma_f32_16x16x32_bf16(e0b[tt], zfa0, ee, 0, 0, 0);
      a = __builtin_amdgcn_mfma_f32_16x16x32_bf16(e1b[tt], zfa1, a, 0, 0, 0);
      f32x4 b = __builtin_amdgcn_mfma_f32_16x16x32_bf16(e0b[tt], zfb0, ee, 0, 0, 0);
      b = __builtin_amdgcn_mfma_f32_16x16x32_bf16(e1b[tt], zfb1, b, 0, 0, 0);
      const unsigned tw = (unsigned)(t * 16);
      {
        const unsigned t0 = (__float_as_uint(a[0]) & 0xFFFFFC00u) | (k4 + 0);
        const unsigned t1 = (__float_as_uint(a[1]) & 0xFFFFFC00u) | (k4 + 1);
        const unsigned t2 = (__float_as_uint(a[2]) & 0xFFFFFC00u) | (k4 + 2);
        const unsigned t3 = (__float_as_uint(a[3]) & 0xFFFFFC00u) | (k4 + 3);
        rka = min(rka, min(min(t0, t1), min(t2, t3)) + tw);
      }
      {
        const unsigned t0 = (__float_as_uint(b[0]) & 0xFFFFFC00u) | (k4 + 0);
        const unsigned t1 = (__float_as_uint(b[1]) & 0xFFFFFC00u) | (k4 + 1);
        const unsigned t2 = (__float_as_uint(b[2]) & 0xFFFFFC00u) | (k4 + 2);
        const unsigned t3 = (__float_as_uint(b[3]) & 0xFFFFFC00u) | (k4 + 3);
        rkb = min(rkb, min(min(t0, t1), min(t2, t3)) + tw);
      }
    }
    // 6) reduce across the 4 ksl groups; store per-wave keys
    rka = min(rka, (unsigned)__shfl_xor((int)rka, 16, 64));
    rka = min(rka, (unsigned)__shfl_xor((int)rka, 32, 64));
    rkb = min(rkb, (unsigned)__shfl_xor((int)rkb, 16, 64));
    rkb = min(rkb, (unsigned)__shfl_xor((int)rkb, 32, 64));
    if (ksl == 0) {
      wkey[(size_t)(rbase + lr) * 8 + wave] = rka;
      wkey[(size_t)(rbase + 16 + lr) * 8 + wave] = rkb;
    }
  }
}

// ---- K2: combine 8 per-wave keys, gather z_q, partials ---------------------
// 2048 blocks x 256 thr; 64 rows/block, 4 threads per row.
__global__ void __launch_bounds__(256) vq_out(
    const float* __restrict__ emb, float* __restrict__ out,
    char* __restrict__ ws) {
  const int tid = threadIdx.x;
  const int wave = tid >> 6, lane = tid & 63;
  const int row = tid >> 2, seg = tid & 3;
  const size_t rowg = (size_t)blockIdx.x * 64 + row;

  const unsigned* wkey = (const unsigned*)(ws + WS_KEY);
  const float* wzz = (const float*)(ws + WS_ZZ);

  unsigned k = 0xFFFFFFFFu;
  if (seg < 2) {
    const uint4 kk = ((const uint4*)(wkey + rowg * 8))[seg];
    k = min(min(kk.x, kk.y), min(kk.z, kk.w));
  }
  k = min(k, (unsigned)__shfl_xor((int)k, 1, 64));        // seg0<->seg1
  k = (unsigned)__shfl((int)k, (lane & 0x3C), 64);        // broadcast in row group
  const unsigned idx = k & 1023u;

  const f32x4* ep = (const f32x4*)(emb + (size_t)idx * 64 + seg * 16);
  f32x4* op = (f32x4*)(out + rowg * 64 + seg * 16);
#pragma unroll
  for (int c = 0; c < 4; ++c) op[c] = ep[c];

  float ls = 0.f; int s1 = 0, s2 = 0;
  if (seg == 0) {
    // d = ||z||^2 + (ee - 2 z.e)_min ; value has low 10 bits cleared
    ls = wzz[rowg] + __uint_as_float(k & 0xFFFFFC00u) - 0.5f;
    s1 = (int)idx;
    s2 = (int)(idx * idx);
    out[OUT_IDX + rowg] = (float)idx;
  }
#pragma unroll
  for (int off = 1; off < 64; off <<= 1) {
    ls += __shfl_xor(ls, off, 64);
    s1 += __shfl_xor(s1, off, 64);
    s2 += __shfl_xor(s2, off, 64);
  }
  __shared__ float sL[4];
  __shared__ int sA[4], sB[4];
  if (lane == 0) { sL[wave] = ls; sA[wave] = s1; sB[wave] = s2; }
  __syncthreads();
  if (tid == 0) {
    float L = 0; int a = 0, b = 0;
#pragma unroll
    for (int w = 0; w < 4; ++w) { L += sL[w]; a += sA[w]; b += sB[w]; }
    ((float*)(ws + WS_LOSS))[blockIdx.x] = L;
    ((int*)(ws + WS_S1))[blockIdx.x] = a;
    ((int*)(ws + WS_S2))[blockIdx.x] = b;
  }
}

// ---- K3: final scalar reduce over 2048 block partials ---------------------
__global__ void vq_final(float* __restrict__ out, const char* __restrict__ ws) {
  const int t = threadIdx.x;   // 256 threads
  const float* lp = (const float*)(ws + WS_LOSS);
  const int* p1 = (const int*)(ws + WS_S1);
  const int* p2 = (const int*)(ws + WS_S2);
  double L = 0; long long a = 0, b = 0;
#pragma unroll
  for (int kk = 0; kk < 8; ++kk) {
    const int i = t + 256 * kk;
    L += (double)lp[i];
    a += (long long)p1[i];
    b += (long long)p2[i];
  }
#pragma unroll
  for (int off = 1; off < 64; off <<= 1) {
    L += __shfl_xor(L, off, 64);
    a += __shfl_xor(a, off, 64);
    b += __shfl_xor(b, off, 64);
  }
  __shared__ double sL[4];
  __shared__ long long sA[4], sB[4];
  const int wave = t >> 6, lane = t & 63;
  if (lane == 0) { sL[wave] = L; sA[wave] = a; sB[wave] = b; }
  __syncthreads();
  if (t == 0) {
    double Lt = 0; long long at = 0, bt = 0;
#pragma unroll
    for (int w = 0; w < 4; ++w) { Lt += sL[w]; at += sA[w]; bt += sB[w]; }
    // loss = (beta + 1) * mean((z_q - z)^2), beta = 0.25
    out[OUT_LOSS] = (float)(1.25 * Lt / 8388608.0);
    // var(idx, ddof=1) exact: (n*S2 - S1^2) / (n*(n-1))
    long long num = bt * 131072LL - at * at;
    out[OUT_VAR] = (float)((double)num / (131072.0 * 131071.0));
  }
}

extern "C" void kernel_launch(void* const* d_in, const int* in_sizes, int n_in,
                              void* d_out, int out_size, void* d_ws, size_t ws_size,
                              hipStream_t stream) {
  (void)in_sizes; (void)n_in; (void)out_size; (void)ws_size;
  const float* z = (const float*)d_in[0];
  const float* emb = (const float*)d_in[1];
  float* out = (float*)d_out;
  char* ws = (char*)d_ws;
  vq_prep<<<64, 64, 0, stream>>>(emb, ws);
  vq_dist<<<1024, 512, 0, stream>>>(z, ws);
  vq_out<<<2048, 256, 0, stream>>>(emb, out, ws);
  vq_final<<<1, 256, 0, stream>>>(out, ws);
}

// Round 7
// 46.895 us; speedup vs baseline: 4.0452x; 4.0452x over previous
//
#include <hip/hip_runtime.h>
#include <stdint.h>

// VQ-VAE quantization: B=131072 rows of z (D=64) vs N_E=1024 codes.
// Outputs (flat f32): z_q [131072*64] | loss [1] | idx [131072] | var(idx,ddof=1) [1]
//
// R7: z-stationary waves (32 rows, 16 VGPR), codes streamed via LDS phases.
//  - R1-R6 lesson: the allocator caps at 64-88 VGPR (2nd launch_bounds arg
//    behaves like CUDA blocks/CU); any >64-VGPR-stationary design remats or
//    spills. So keep per-wave state tiny and share code tiles through LDS.
//  K0 vq_prep: codebook -> -2e bf16 MFMA A-frags + ||e||^2+0.5.
//  K1 vq_main: 1024 blocks x 256 thr; wave handles 32 rows x all 1024 codes;
//     8 phases x 16KB frags via global_load_lds; fused gather/write epilogue.
//  K2 vq_final: scalar reduce of 1024 block partials.
// key = (float_bits(0.5+||e||^2-2z.e) & ~1023) | code ; unsigned min == argmin.

typedef __attribute__((ext_vector_type(8))) __bf16 bf16x8;
typedef __attribute__((ext_vector_type(4))) float f32x4;

#define OUT_LOSS 8388608
#define OUT_IDX  8388609
#define OUT_VAR  8519681

// workspace layout (bytes)
#define WS_LOSS  0          // float[1024] per-block loss partials
#define WS_S1    4096       // int[1024] sum(idx)
#define WS_S2    8192       // int[1024] sum(idx^2)
#define WS_EFRAG 12288      // bf16x8[64 tiles * 2 ksteps * 64 lanes] = 128 KB
#define WS_EE    143360     // float[1024] ||e||^2 + 0.5 (4 KB)

__device__ __forceinline__ void gld_lds16(const void* g, void* l) {
  __builtin_amdgcn_global_load_lds(
      (const __attribute__((address_space(1))) unsigned*)g,
      (__attribute__((address_space(3))) unsigned*)l, 16, 0, 0);
}

// ---- K0: prep codebook fragments -----------------------------------------
// A-frag for mfma_f32_16x16x32_bf16: lane l holds code row (t*16 + (l&15)),
// k = kstep*32 + (l>>4)*8 + i. Values are -2*e.
__global__ void vq_prep(const float* __restrict__ emb, char* __restrict__ ws) {
  bf16x8* efrag = (bf16x8*)(ws + WS_EFRAG);
  float* eeoff = (float*)(ws + WS_EE);
  const int t = blockIdx.x;    // tile 0..63
  const int l = threadIdx.x;   // 0..63
  const int n = t * 16 + (l & 15);
  const int kb0 = (l >> 4) * 8;
  const float* er = emb + n * 64;
  for (int j = 0; j < 2; ++j) {
    const int kb = j * 32 + kb0;
    bf16x8 h;
#pragma unroll
    for (int i = 0; i < 8; ++i) h[i] = (__bf16)(-2.0f * er[kb + i]);
    efrag[(t * 2 + j) * 64 + l] = h;
  }
  if (l < 16) {
    const float* e2 = emb + (t * 16 + l) * 64;
    float s = 0.f;
#pragma unroll
    for (int d = 0; d < 64; ++d) s += e2[d] * e2[d];
    eeoff[t * 16 + l] = s + 0.5f;
  }
}

// ---- K1: distances + argmin + fused epilogue ------------------------------
// 1024 blocks x 256 thr (4 waves); wave w owns rows blockIdx*128 + w*32 .. +31.
__global__ void __launch_bounds__(256) vq_main(
    const float* __restrict__ z, const float* __restrict__ emb,
    float* __restrict__ out, char* __restrict__ ws) {
  __shared__ char smfrag[16384];     // one 8-tile phase of code fragments
  __shared__ float see[1024];        // ||e||^2 + 0.5 table
  __shared__ float sL[4];
  __shared__ int sA[4], sB[4];

  const int tid = threadIdx.x;
  const int wave = tid >> 6, lane = tid & 63;
  const int lr = lane & 15, ksl = lane >> 4;
  const int k0 = ksl * 8;
  const int row_base = blockIdx.x * 128 + wave * 32;

  // async stage: ee table (4 KB, once) + phase-0 frags (16 KB)
  gld_lds16(ws + WS_EE + wave * 1024 + lane * 16, (char*)see + wave * 1024);
#pragma unroll
  for (int i = 0; i < 4; ++i)
    gld_lds16(ws + WS_EFRAG + i * 4096 + wave * 1024 + lane * 16,
              smfrag + i * 4096 + wave * 1024);

  // z prologue: rows row_base+lr (A) and row_base+16+lr (B), this lane's
  // 16 dims (k = ksl*8 + 0..7 of each 32-half). B-frag col = lane&15.
  bf16x8 zfa0, zfa1, zfb0, zfb1;
  float zza, zzb;
  {
    const float* zra = z + (size_t)(row_base + lr) * 64;
    const float* zrb = z + (size_t)(row_base + 16 + lr) * 64;
    f32x4 a0 = *(const f32x4*)(zra + k0);
    f32x4 a1 = *(const f32x4*)(zra + k0 + 4);
    f32x4 a2 = *(const f32x4*)(zra + 32 + k0);
    f32x4 a3 = *(const f32x4*)(zra + 32 + k0 + 4);
    f32x4 b0 = *(const f32x4*)(zrb + k0);
    f32x4 b1 = *(const f32x4*)(zrb + k0 + 4);
    f32x4 b2 = *(const f32x4*)(zrb + 32 + k0);
    f32x4 b3 = *(const f32x4*)(zrb + 32 + k0 + 4);
    float sa = 0.f, sb = 0.f;
#pragma unroll
    for (int i = 0; i < 4; ++i) {
      zfa0[i] = (__bf16)a0[i]; zfa0[4 + i] = (__bf16)a1[i];
      zfa1[i] = (__bf16)a2[i]; zfa1[4 + i] = (__bf16)a3[i];
      zfb0[i] = (__bf16)b0[i]; zfb0[4 + i] = (__bf16)b1[i];
      zfb1[i] = (__bf16)b2[i]; zfb1[4 + i] = (__bf16)b3[i];
      sa += a0[i] * a0[i] + a1[i] * a1[i] + a2[i] * a2[i] + a3[i] * a3[i];
      sb += b0[i] * b0[i] + b1[i] * b1[i] + b2[i] * b2[i] + b3[i] * b3[i];
    }
    sa += __shfl_xor(sa, 16, 64); sa += __shfl_xor(sa, 32, 64);
    sb += __shfl_xor(sb, 16, 64); sb += __shfl_xor(sb, 32, 64);
    zza = sa; zzb = sb;   // full ||z||^2, replicated across ksl groups
  }

  unsigned rka = 0xFFFFFFFFu, rkb = 0xFFFFFFFFu;
  const unsigned k4 = (unsigned)(ksl * 4);
  const bf16x8* sfrag = (const bf16x8*)smfrag;

  for (int ph = 0; ph < 8; ++ph) {
    __syncthreads();               // staged phase visible (drains vmcnt too)
#pragma unroll
    for (int tt = 0; tt < 8; ++tt) {
      const int g = ph * 8 + tt;   // global code tile
      bf16x8 e0 = sfrag[(tt * 2 + 0) * 64 + lane];   // conflict-free b128
      bf16x8 e1 = sfrag[(tt * 2 + 1) * 64 + lane];
      const f32x4 ee = *(const f32x4*)(see + g * 16 + ksl * 4);
      f32x4 a = __builtin_amdgcn_mfma_f32_16x16x32_bf16(e0, zfa0, ee, 0, 0, 0);
      a = __builtin_amdgcn_mfma_f32_16x16x32_bf16(e1, zfa1, a, 0, 0, 0);
      f32x4 b = __builtin_amdgcn_mfma_f32_16x16x32_bf16(e0, zfb0, ee, 0, 0, 0);
      b = __builtin_amdgcn_mfma_f32_16x16x32_bf16(e1, zfb1, b, 0, 0, 0);
      const unsigned tw = (unsigned)(g * 16);
      {
        const unsigned t0 = (__float_as_uint(a[0]) & 0xFFFFFC00u) | (k4 + 0);
        const unsigned t1 = (__float_as_uint(a[1]) & 0xFFFFFC00u) | (k4 + 1);
        const unsigned t2 = (__float_as_uint(a[2]) & 0xFFFFFC00u) | (k4 + 2);
        const unsigned t3 = (__float_as_uint(a[3]) & 0xFFFFFC00u) | (k4 + 3);
        rka = min(rka, min(min(t0, t1), min(t2, t3)) + tw);
      }
      {
        const unsigned t0 = (__float_as_uint(b[0]) & 0xFFFFFC00u) | (k4 + 0);
        const unsigned t1 = (__float_as_uint(b[1]) & 0xFFFFFC00u) | (k4 + 1);
        const unsigned t2 = (__float_as_uint(b[2]) & 0xFFFFFC00u) | (k4 + 2);
        const unsigned t3 = (__float_as_uint(b[3]) & 0xFFFFFC00u) | (k4 + 3);
        rkb = min(rkb, min(min(t0, t1), min(t2, t3)) + tw);
      }
    }
    __syncthreads();               // all waves done reading this phase
    if (ph < 7) {
#pragma unroll
      for (int i = 0; i < 4; ++i)
        gld_lds16(ws + WS_EFRAG + (ph + 1) * 16384 + i * 4096 + wave * 1024 + lane * 16,
                  smfrag + i * 4096 + wave * 1024);
    }
  }

  // per-row final keys: reduce across the 4 ksl lane groups
  rka = min(rka, (unsigned)__shfl_xor((int)rka, 16, 64));
  rka = min(rka, (unsigned)__shfl_xor((int)rka, 32, 64));
  rkb = min(rkb, (unsigned)__shfl_xor((int)rkb, 16, 64));
  rkb = min(rkb, (unsigned)__shfl_xor((int)rkb, 32, 64));

  // fused epilogue: 2 lanes per row (erow 0..31), gather z_q, write idx,
  // accumulate loss/var partials.
  const int erow = lane >> 1, eseg = lane & 1;
  const int src = erow & 15;   // source lane holding this row's key (ksl=0 grp)
  const unsigned ka = (unsigned)__shfl((int)rka, src, 64);
  const unsigned kb = (unsigned)__shfl((int)rkb, src, 64);
  const float za = __shfl(zza, src, 64);
  const float zb = __shfl(zzb, src, 64);
  const unsigned k = (erow < 16) ? ka : kb;
  const float zzv = (erow < 16) ? za : zb;
  const unsigned idx = k & 1023u;
  const size_t rowg = (size_t)row_base + erow;
  const f32x4* ep = (const f32x4*)(emb + (size_t)idx * 64 + eseg * 32);
  f32x4* op = (f32x4*)(out + rowg * 64 + eseg * 32);
#pragma unroll
  for (int c = 0; c < 8; ++c) op[c] = ep[c];

  float ls = 0.f; int s1 = 0, s2 = 0;
  if (eseg == 0) {
    // d = ||z||^2 + (0.5 + ee - 2 z.e)_min - 0.5 ; low 10 bits were cleared
    ls = zzv + __uint_as_float(k & 0xFFFFFC00u) - 0.5f;
    s1 = (int)idx;
    s2 = (int)(idx * idx);
    out[OUT_IDX + rowg] = (float)idx;
  }
#pragma unroll
  for (int off = 1; off < 64; off <<= 1) {
    ls += __shfl_xor(ls, off, 64);
    s1 += __shfl_xor(s1, off, 64);
    s2 += __shfl_xor(s2, off, 64);
  }
  if (lane == 0) { sL[wave] = ls; sA[wave] = s1; sB[wave] = s2; }
  __syncthreads();
  if (tid == 0) {
    float L = 0; int a = 0, b = 0;
#pragma unroll
    for (int w = 0; w < 4; ++w) { L += sL[w]; a += sA[w]; b += sB[w]; }
    ((float*)(ws + WS_LOSS))[blockIdx.x] = L;
    ((int*)(ws + WS_S1))[blockIdx.x] = a;
    ((int*)(ws + WS_S2))[blockIdx.x] = b;
  }
}

// ---- K2: final scalar reduce over 1024 block partials ---------------------
__global__ void vq_final(float* __restrict__ out, const char* __restrict__ ws) {
  const int t = threadIdx.x;   // 256 threads
  const float* lp = (const float*)(ws + WS_LOSS);
  const int* p1 = (const int*)(ws + WS_S1);
  const int* p2 = (const int*)(ws + WS_S2);
  double L = 0; long long a = 0, b = 0;
#pragma unroll
  for (int kk = 0; kk < 4; ++kk) {
    const int i = t + 256 * kk;
    L += (double)lp[i];
    a += (long long)p1[i];
    b += (long long)p2[i];
  }
#pragma unroll
  for (int off = 1; off < 64; off <<= 1) {
    L += __shfl_xor(L, off, 64);
    a += __shfl_xor(a, off, 64);
    b += __shfl_xor(b, off, 64);
  }
  __shared__ double sL[4];
  __shared__ long long sA[4], sB[4];
  const int wave = t >> 6, lane = t & 63;
  if (lane == 0) { sL[wave] = L; sA[wave] = a; sB[wave] = b; }
  __syncthreads();
  if (t == 0) {
    double Lt = 0; long long at = 0, bt = 0;
#pragma unroll
    for (int w = 0; w < 4; ++w) { Lt += sL[w]; at += sA[w]; bt += sB[w]; }
    // loss = (beta + 1) * mean((z_q - z)^2), beta = 0.25
    out[OUT_LOSS] = (float)(1.25 * Lt / 8388608.0);
    // var(idx, ddof=1) exact: (n*S2 - S1^2) / (n*(n-1))
    long long num = bt * 131072LL - at * at;
    out[OUT_VAR] = (float)((double)num / (131072.0 * 131071.0));
  }
}

extern "C" void kernel_launch(void* const* d_in, const int* in_sizes, int n_in,
                              void* d_out, int out_size, void* d_ws, size_t ws_size,
                              hipStream_t stream) {
  (void)in_sizes; (void)n_in; (void)out_size; (void)ws_size;
  const float* z = (const float*)d_in[0];
  const float* emb = (const float*)d_in[1];
  float* out = (float*)d_out;
  char* ws = (char*)d_ws;
  vq_prep<<<64, 64, 0, stream>>>(emb, ws);
  vq_main<<<1024, 256, 0, stream>>>(z, emb, out, ws);
  vq_final<<<1, 256, 0, stream>>>(out, ws);
}

// Round 8
// 45.699 us; speedup vs baseline: 4.1511x; 1.0262x over previous
//
#include <hip/hip_runtime.h>
#include <stdint.h>

// VQ-VAE quantization: B=131072 rows of z (D=64) vs N_E=1024 codes.
// Outputs (flat f32): z_q [131072*64] | loss [1] | idx [131072] | var(idx,ddof=1) [1]
//
// R8 = R7 + T3/T4 (double-buffered LDS staging, raw s_barrier, counted
// s_waitcnt vmcnt(4) that never drains to 0 in the loop). R7's single-buffer
// staging exposed the full global->LDS latency at every phase barrier
// (compiler emits vmcnt(0) before __syncthreads); that was ~70% of its 41us.
// key = (float_bits(0.5+||e||^2-2z.e) & ~1023) | code ; unsigned min == argmin.

typedef __attribute__((ext_vector_type(8))) __bf16 bf16x8;
typedef __attribute__((ext_vector_type(4))) float f32x4;

#define OUT_LOSS 8388608
#define OUT_IDX  8388609
#define OUT_VAR  8519681

// workspace layout (bytes)
#define WS_LOSS  0          // float[1024] per-block loss partials
#define WS_S1    4096       // int[1024] sum(idx)
#define WS_S2    8192       // int[1024] sum(idx^2)
#define WS_EFRAG 12288      // bf16x8[64 tiles * 2 ksteps * 64 lanes] = 128 KB
#define WS_EE    143360     // float[1024] ||e||^2 + 0.5 (4 KB)

__device__ __forceinline__ void gld_lds16(const void* g, void* l) {
  __builtin_amdgcn_global_load_lds(
      (const __attribute__((address_space(1))) unsigned*)g,
      (__attribute__((address_space(3))) unsigned*)l, 16, 0, 0);
}

// ---- K0: prep codebook fragments -----------------------------------------
// A-frag for mfma_f32_16x16x32_bf16: lane l holds code row (t*16 + (l&15)),
// k = kstep*32 + (l>>4)*8 + i. Values are -2*e.
__global__ void vq_prep(const float* __restrict__ emb, char* __restrict__ ws) {
  bf16x8* efrag = (bf16x8*)(ws + WS_EFRAG);
  float* eeoff = (float*)(ws + WS_EE);
  const int t = blockIdx.x;    // tile 0..63
  const int l = threadIdx.x;   // 0..63
  const int n = t * 16 + (l & 15);
  const int kb0 = (l >> 4) * 8;
  const float* er = emb + n * 64;
  for (int j = 0; j < 2; ++j) {
    const int kb = j * 32 + kb0;
    bf16x8 h;
#pragma unroll
    for (int i = 0; i < 8; ++i) h[i] = (__bf16)(-2.0f * er[kb + i]);
    efrag[(t * 2 + j) * 64 + l] = h;
  }
  if (l < 16) {
    const float* e2 = emb + (t * 16 + l) * 64;
    float s = 0.f;
#pragma unroll
    for (int d = 0; d < 64; ++d) s += e2[d] * e2[d];
    eeoff[t * 16 + l] = s + 0.5f;
  }
}

// ---- K1: distances + argmin + fused epilogue ------------------------------
// 1024 blocks x 256 thr (4 waves); wave w owns rows blockIdx*128 + w*32 .. +31.
__global__ void __launch_bounds__(256) vq_main(
    const float* __restrict__ z, const float* __restrict__ emb,
    float* __restrict__ out, char* __restrict__ ws) {
  __shared__ char smfrag[2][16384];   // double-buffered 8-tile phases
  __shared__ float see[1024];         // ||e||^2 + 0.5 table
  __shared__ float sL[4];
  __shared__ int sA[4], sB[4];

  const int tid = threadIdx.x;
  const int wave = tid >> 6, lane = tid & 63;
  const int lr = lane & 15, ksl = lane >> 4;
  const int k0 = ksl * 8;
  const int row_base = blockIdx.x * 128 + wave * 32;

#define STAGE(ph, buf)                                                         \
  {                                                                            \
    _Pragma("unroll")                                                          \
    for (int i_ = 0; i_ < 4; ++i_)                                             \
      gld_lds16(ws + WS_EFRAG + (ph) * 16384 + i_ * 4096 + wave * 1024 + lane * 16, \
                smfrag[buf] + i_ * 4096 + wave * 1024);                        \
  }

  // prologue staging: ee (oldest), then ph0->buf0, ph1->buf1 (9 loads/wave)
  gld_lds16(ws + WS_EE + wave * 1024 + lane * 16, (char*)see + wave * 1024);
  STAGE(0, 0);
  STAGE(1, 1);

  // z prologue (overlaps staging latency): rows row_base+lr (A) and
  // row_base+16+lr (B), this lane's 16 dims. B-frag col = lane&15.
  bf16x8 zfa0, zfa1, zfb0, zfb1;
  float zza, zzb;
  {
    const float* zra = z + (size_t)(row_base + lr) * 64;
    const float* zrb = z + (size_t)(row_base + 16 + lr) * 64;
    f32x4 a0 = *(const f32x4*)(zra + k0);
    f32x4 a1 = *(const f32x4*)(zra + k0 + 4);
    f32x4 a2 = *(const f32x4*)(zra + 32 + k0);
    f32x4 a3 = *(const f32x4*)(zra + 32 + k0 + 4);
    f32x4 b0 = *(const f32x4*)(zrb + k0);
    f32x4 b1 = *(const f32x4*)(zrb + k0 + 4);
    f32x4 b2 = *(const f32x4*)(zrb + 32 + k0);
    f32x4 b3 = *(const f32x4*)(zrb + 32 + k0 + 4);
    float sa = 0.f, sb = 0.f;
#pragma unroll
    for (int i = 0; i < 4; ++i) {
      zfa0[i] = (__bf16)a0[i]; zfa0[4 + i] = (__bf16)a1[i];
      zfa1[i] = (__bf16)a2[i]; zfa1[4 + i] = (__bf16)a3[i];
      zfb0[i] = (__bf16)b0[i]; zfb0[4 + i] = (__bf16)b1[i];
      zfb1[i] = (__bf16)b2[i]; zfb1[4 + i] = (__bf16)b3[i];
      sa += a0[i] * a0[i] + a1[i] * a1[i] + a2[i] * a2[i] + a3[i] * a3[i];
      sb += b0[i] * b0[i] + b1[i] * b1[i] + b2[i] * b2[i] + b3[i] * b3[i];
    }
    sa += __shfl_xor(sa, 16, 64); sa += __shfl_xor(sa, 32, 64);
    sb += __shfl_xor(sb, 16, 64); sb += __shfl_xor(sb, 32, 64);
    zza = sa; zzb = sb;   // full ||z||^2, replicated across ksl groups
  }

  unsigned rka = 0xFFFFFFFFu, rkb = 0xFFFFFFFFu;
  const unsigned k4 = (unsigned)(ksl * 4);

#pragma unroll
  for (int ph = 0; ph < 8; ++ph) {
    // phase ph's 4 staging loads done; phase ph+1's may stay in flight.
    if (ph < 7) { asm volatile("s_waitcnt vmcnt(4)" ::: "memory"); }
    else       { asm volatile("s_waitcnt vmcnt(0)" ::: "memory"); }
    __builtin_amdgcn_sched_barrier(0);      // rule #18: pin code after wait
    __builtin_amdgcn_s_barrier();           // raw barrier: no vmcnt(0) drain
    const bf16x8* sfrag = (const bf16x8*)(smfrag[ph & 1]);
#pragma unroll
    for (int tt = 0; tt < 8; ++tt) {
      const int g = ph * 8 + tt;   // global code tile
      bf16x8 e0 = sfrag[(tt * 2 + 0) * 64 + lane];   // conflict-free b128
      bf16x8 e1 = sfrag[(tt * 2 + 1) * 64 + lane];
      const f32x4 ee = *(const f32x4*)(see + g * 16 + ksl * 4);
      f32x4 a = __builtin_amdgcn_mfma_f32_16x16x32_bf16(e0, zfa0, ee, 0, 0, 0);
      a = __builtin_amdgcn_mfma_f32_16x16x32_bf16(e1, zfa1, a, 0, 0, 0);
      f32x4 b = __builtin_amdgcn_mfma_f32_16x16x32_bf16(e0, zfb0, ee, 0, 0, 0);
      b = __builtin_amdgcn_mfma_f32_16x16x32_bf16(e1, zfb1, b, 0, 0, 0);
      const unsigned tw = (unsigned)(g * 16);
      {
        const unsigned t0 = (__float_as_uint(a[0]) & 0xFFFFFC00u) | (k4 + 0);
        const unsigned t1 = (__float_as_uint(a[1]) & 0xFFFFFC00u) | (k4 + 1);
        const unsigned t2 = (__float_as_uint(a[2]) & 0xFFFFFC00u) | (k4 + 2);
        const unsigned t3 = (__float_as_uint(a[3]) & 0xFFFFFC00u) | (k4 + 3);
        rka = min(rka, min(min(t0, t1), min(t2, t3)) | tw);
      }
      {
        const unsigned t0 = (__float_as_uint(b[0]) & 0xFFFFFC00u) | (k4 + 0);
        const unsigned t1 = (__float_as_uint(b[1]) & 0xFFFFFC00u) | (k4 + 1);
        const unsigned t2 = (__float_as_uint(b[2]) & 0xFFFFFC00u) | (k4 + 2);
        const unsigned t3 = (__float_as_uint(b[3]) & 0xFFFFFC00u) | (k4 + 3);
        rkb = min(rkb, min(min(t0, t1), min(t2, t3)) | tw);
      }
    }
    __builtin_amdgcn_s_barrier();           // all waves done reading buf
    if (ph < 6) STAGE(ph + 2, ph & 1);      // refill the buffer just freed
  }
#undef STAGE

  // per-row final keys: reduce across the 4 ksl lane groups
  rka = min(rka, (unsigned)__shfl_xor((int)rka, 16, 64));
  rka = min(rka, (unsigned)__shfl_xor((int)rka, 32, 64));
  rkb = min(rkb, (unsigned)__shfl_xor((int)rkb, 16, 64));
  rkb = min(rkb, (unsigned)__shfl_xor((int)rkb, 32, 64));

  // fused epilogue: 2 lanes per row (erow 0..31), gather z_q, write idx,
  // accumulate loss/var partials.
  const int erow = lane >> 1, eseg = lane & 1;
  const int src = erow & 15;   // source lane holding this row's key (ksl=0 grp)
  const unsigned ka = (unsigned)__shfl((int)rka, src, 64);
  const unsigned kb = (unsigned)__shfl((int)rkb, src, 64);
  const float za = __shfl(zza, src, 64);
  const float zb = __shfl(zzb, src, 64);
  const unsigned k = (erow < 16) ? ka : kb;
  const float zzv = (erow < 16) ? za : zb;
  const unsigned idx = k & 1023u;
  const size_t rowg = (size_t)row_base + erow;
  const f32x4* ep = (const f32x4*)(emb + (size_t)idx * 64 + eseg * 32);
  f32x4* op = (f32x4*)(out + rowg * 64 + eseg * 32);
#pragma unroll
  for (int c = 0; c < 8; ++c) op[c] = ep[c];

  float ls = 0.f; int s1 = 0, s2 = 0;
  if (eseg == 0) {
    // d = ||z||^2 + (0.5 + ee - 2 z.e)_min - 0.5 ; low 10 bits were cleared
    ls = zzv + __uint_as_float(k & 0xFFFFFC00u) - 0.5f;
    s1 = (int)idx;
    s2 = (int)(idx * idx);
    out[OUT_IDX + rowg] = (float)idx;
  }
#pragma unroll
  for (int off = 1; off < 64; off <<= 1) {
    ls += __shfl_xor(ls, off, 64);
    s1 += __shfl_xor(s1, off, 64);
    s2 += __shfl_xor(s2, off, 64);
  }
  if (lane == 0) { sL[wave] = ls; sA[wave] = s1; sB[wave] = s2; }
  __syncthreads();
  if (tid == 0) {
    float L = 0; int a = 0, b = 0;
#pragma unroll
    for (int w = 0; w < 4; ++w) { L += sL[w]; a += sA[w]; b += sB[w]; }
    ((float*)(ws + WS_LOSS))[blockIdx.x] = L;
    ((int*)(ws + WS_S1))[blockIdx.x] = a;
    ((int*)(ws + WS_S2))[blockIdx.x] = b;
  }
}

// ---- K2: final scalar reduce over 1024 block partials ---------------------
__global__ void vq_final(float* __restrict__ out, const char* __restrict__ ws) {
  const int t = threadIdx.x;   // 256 threads
  const float* lp = (const float*)(ws + WS_LOSS);
  const int* p1 = (const int*)(ws + WS_S1);
  const int* p2 = (const int*)(ws + WS_S2);
  double L = 0; long long a = 0, b = 0;
#pragma unroll
  for (int kk = 0; kk < 4; ++kk) {
    const int i = t + 256 * kk;
    L += (double)lp[i];
    a += (long long)p1[i];
    b += (long long)p2[i];
  }
#pragma unroll
  for (int off = 1; off < 64; off <<= 1) {
    L += __shfl_xor(L, off, 64);
    a += __shfl_xor(a, off, 64);
    b += __shfl_xor(b, off, 64);
  }
  __shared__ double sL[4];
  __shared__ long long sA[4], sB[4];
  const int wave = t >> 6, lane = t & 63;
  if (lane == 0) { sL[wave] = L; sA[wave] = a; sB[wave] = b; }
  __syncthreads();
  if (t == 0) {
    double Lt = 0; long long at = 0, bt = 0;
#pragma unroll
    for (int w = 0; w < 4; ++w) { Lt += sL[w]; at += sA[w]; bt += sB[w]; }
    // loss = (beta + 1) * mean((z_q - z)^2), beta = 0.25
    out[OUT_LOSS] = (float)(1.25 * Lt / 8388608.0);
    // var(idx, ddof=1) exact: (n*S2 - S1^2) / (n*(n-1))
    long long num = bt * 131072LL - at * at;
    out[OUT_VAR] = (float)((double)num / (131072.0 * 131071.0));
  }
}

extern "C" void kernel_launch(void* const* d_in, const int* in_sizes, int n_in,
                              void* d_out, int out_size, void* d_ws, size_t ws_size,
                              hipStream_t stream) {
  (void)in_sizes; (void)n_in; (void)out_size; (void)ws_size;
  const float* z = (const float*)d_in[0];
  const float* emb = (const float*)d_in[1];
  float* out = (float*)d_out;
  char* ws = (char*)d_ws;
  vq_prep<<<64, 64, 0, stream>>>(emb, ws);
  vq_main<<<1024, 256, 0, stream>>>(z, emb, out, ws);
  vq_final<<<1, 256, 0, stream>>>(out, ws);
}